// Round 14
// baseline (130.406 us; speedup 1.0000x reference)
//
#include <hip/hip_runtime.h>
#include <hip/hip_bf16.h>

#define GRID_RES 32
#define GRID_DIM 8
#define N_CELLS  256
#define EMB_VOL  512
#define TAB_N    (GRID_RES * GRID_RES * GRID_RES)   // 32768
#define NPT      4
#define BLOCK    1024

typedef float vf4 __attribute__((ext_vector_type(4)));   // nontemporal-capable

// Sparse trilinear interp + analytic gradient. Exact fp32, branchless.
// R12 body (register-packed, LDS int16 table, float4 I/O) + NONTEMPORAL
// position loads and output stores (via clang ext_vector_type float4):
// streaming data (24MB pos in, 39MB out) no longer allocates in L2,
// reserving L2 for the embeddings (the only reuse-bearing data).
__global__ __launch_bounds__(BLOCK) void neural_poisson_interp(
    const float* __restrict__ positions,   // [N,3]
    const float* __restrict__ embeddings,  // [NUM_EMB, 512]
    const int*   __restrict__ block_table, // [32,32,32]
    float* __restrict__ out,               // emb[N] | grad[N,3] | mask[N]
    int n)
{
    __shared__ short stab[TAB_N];          // 64 KB, int16 block ids
    {
        const int4* t4 = reinterpret_cast<const int4*>(block_table);
        for (int k = threadIdx.x; k < TAB_N / 4; k += BLOCK) {
            int4 v = t4[k];
            short4 s;
            s.x = (short)v.x; s.y = (short)v.y; s.z = (short)v.z; s.w = (short)v.w;
            *reinterpret_cast<short4*>(&stab[4 * k]) = s;
        }
    }
    __syncthreads();

    float* out_emb  = out;
    float* out_grad = out + (size_t)n;
    float* out_mask = out + 4 * (size_t)n;

    int nq = (n + NPT - 1) / NPT;
    int stride = gridDim.x * BLOCK;
    for (int q = blockIdx.x * BLOCK + threadIdx.x; q < nq; q += stride) {
        int i0 = q * NPT;
        bool full = (i0 + NPT <= n);

        float px[NPT], py[NPT], pz[NPT];
        if (full) {
            const vf4* p4 = reinterpret_cast<const vf4*>(positions + 3 * (size_t)i0);
            vf4 A = __builtin_nontemporal_load(p4 + 0);
            vf4 B = __builtin_nontemporal_load(p4 + 1);
            vf4 C = __builtin_nontemporal_load(p4 + 2);
            px[0]=A.x; py[0]=A.y; pz[0]=A.z;
            px[1]=A.w; py[1]=B.x; pz[1]=B.y;
            px[2]=B.z; py[2]=B.w; pz[2]=C.x;
            px[3]=C.y; py[3]=C.z; pz[3]=C.w;
        } else {
#pragma unroll
            for (int p = 0; p < NPT; ++p) {
                int ip = min(i0 + p, n - 1);
                px[p] = positions[3 * ip + 0];
                py[p] = positions[3 * ip + 1];
                pz[p] = positions[3 * ip + 2];
            }
        }

        float fr[NPT][3];      // frac only; weights recomputed in compute phase
        int bpk[NPT][4];       // corner block ids, 2x int16 per int
        int lpk[NPT][4];       // corner local offsets (0..511), 2x per int

#pragma unroll
        for (int p = 0; p < NPT; ++p) {
            float xc[3];
            xc[0] = (px[p] + 1.0f) * 0.5f * (float)(N_CELLS - 1);
            xc[1] = (py[p] + 1.0f) * 0.5f * (float)(N_CELLS - 1);
            xc[2] = (pz[p] + 1.0f) * 0.5f * (float)(N_CELLS - 1);
            int base[3];
#pragma unroll
            for (int a = 0; a < 3; ++a) {
                float bf = fminf(fmaxf(floorf(xc[a]), 0.0f), (float)(N_CELLS - 2));
                fr[p][a] = xc[a] - bf;
                base[a] = (int)bf;
            }
#pragma unroll
            for (int k = 0; k < 4; ++k) {       // corner pair (2k, 2k+1)
                int c0 = 2 * k, c1 = 2 * k + 1;
                int dx0 = (c0 >> 2) & 1, dy0 = (c0 >> 1) & 1, dz0 = c0 & 1;
                int dx1 = (c1 >> 2) & 1, dy1 = (c1 >> 1) & 1, dz1 = c1 & 1;
                int cx0 = base[0] + dx0, cy0 = base[1] + dy0, cz0 = base[2] + dz0;
                int cx1 = base[0] + dx1, cy1 = base[1] + dy1, cz1 = base[2] + dz1;
                int t0 = stab[((cx0 >> 3) * GRID_RES + (cy0 >> 3)) * GRID_RES + (cz0 >> 3)];
                int t1 = stab[((cx1 >> 3) * GRID_RES + (cy1 >> 3)) * GRID_RES + (cz1 >> 3)];
                bpk[p][k] = (t0 & 0xffff) | (t1 << 16);
                int l0 = ((cx0 & 7) * GRID_DIM + (cy0 & 7)) * GRID_DIM + (cz0 & 7);
                int l1 = ((cx1 & 7) * GRID_DIM + (cy1 & 7)) * GRID_DIM + (cz1 & 7);
                lpk[p][k] = l0 | (l1 << 16);
            }
        }

        // all 32 embedding gathers, branchless (clamped index); NOT nontemporal
        // (embeddings are the reuse-bearing data we want L2 to keep)
        float e[NPT][8];
#pragma unroll
        for (int p = 0; p < NPT; ++p)
#pragma unroll
            for (int c = 0; c < 8; ++c) {
                int v = bpk[p][c >> 1];
                int t = (c & 1) ? (v >> 16) : (int)(short)(v & 0xffff);
                int lv = lpk[p][c >> 1];
                int li = (c & 1) ? (lv >> 16) : (lv & 0xffff);
                int b = t > 0 ? t : 0;
                e[p][c] = embeddings[b * EMB_VOL + li];
            }

        const float scale = 0.5f * (float)(N_CELLS - 1);  // 127.5
        float acc[NPT], gxv[NPT], gyv[NPT], gzv[NPT], mk[NPT];

#pragma unroll
        for (int p = 0; p < NPT; ++p) {
            float fx = fr[p][0], fy = fr[p][1], fz = fr[p][2];
            float ox = 1.0f - fx, oy = 1.0f - fy, oz = 1.0f - fz;
            float a = 0.0f, gx = 0.0f, gy = 0.0f, gz = 0.0f;
            int sgn = -1;
#pragma unroll
            for (int c = 0; c < 8; ++c) {
                int dx = (c >> 2) & 1, dy = (c >> 1) & 1, dz = c & 1;
                int v = bpk[p][c >> 1];
                int t = (c & 1) ? (v >> 16) : (int)(short)(v & 0xffff);
                sgn &= t;
                float ev = t >= 0 ? e[p][c] : 0.0f;
                float wx = dx ? fx : ox;
                float wy = dy ? fy : oy;
                float wz = dz ? fz : oz;
                a += wx * wy * wz * ev;
                float tgx = wy * wz * ev;
                float tgy = wx * wz * ev;
                float tgz = wx * wy * ev;
                gx += dx ? tgx : -tgx;
                gy += dy ? tgy : -tgy;
                gz += dz ? tgz : -tgz;
            }
            acc[p] = a;
            gxv[p] = scale * gx;
            gyv[p] = scale * gy;
            gzv[p] = scale * gz;
            mk[p]  = (sgn >= 0) ? 1.0f : 0.0f;
        }

        if (full) {
            vf4 o0; o0.x = acc[0]; o0.y = acc[1]; o0.z = acc[2]; o0.w = acc[3];
            __builtin_nontemporal_store(o0, reinterpret_cast<vf4*>(out_emb + i0));
            vf4* g4 = reinterpret_cast<vf4*>(out_grad + 3 * (size_t)i0);
            vf4 g0; g0.x = gxv[0]; g0.y = gyv[0]; g0.z = gzv[0]; g0.w = gxv[1];
            vf4 g1; g1.x = gyv[1]; g1.y = gzv[1]; g1.z = gxv[2]; g1.w = gyv[2];
            vf4 g2; g2.x = gzv[2]; g2.y = gxv[3]; g2.z = gyv[3]; g2.w = gzv[3];
            __builtin_nontemporal_store(g0, g4 + 0);
            __builtin_nontemporal_store(g1, g4 + 1);
            __builtin_nontemporal_store(g2, g4 + 2);
            vf4 m0; m0.x = mk[0]; m0.y = mk[1]; m0.z = mk[2]; m0.w = mk[3];
            __builtin_nontemporal_store(m0, reinterpret_cast<vf4*>(out_mask + i0));
        } else {
#pragma unroll
            for (int p = 0; p < NPT; ++p) {
                int ip = i0 + p;
                if (ip < n) {
                    out_emb[ip]          = acc[p];
                    out_grad[3 * ip + 0] = gxv[p];
                    out_grad[3 * ip + 1] = gyv[p];
                    out_grad[3 * ip + 2] = gzv[p];
                    out_mask[ip]         = mk[p];
                }
            }
        }
    }
}

extern "C" void kernel_launch(void* const* d_in, const int* in_sizes, int n_in,
                              void* d_out, int out_size, void* d_ws, size_t ws_size,
                              hipStream_t stream) {
    const float* positions   = (const float*)d_in[0];
    const float* embeddings  = (const float*)d_in[1];
    const int*   block_table = (const int*)d_in[2];

    int n = in_sizes[0] / 3;
    int nq = (n + NPT - 1) / NPT;

    float* out = (float*)d_out;

    int grid = 512;                           // persistent: 2 WGs/CU target
    int maxg = (nq + BLOCK - 1) / BLOCK;
    if (grid > maxg) grid = maxg;
    neural_poisson_interp<<<grid, BLOCK, 0, stream>>>(
        positions, embeddings, block_table, out, n);
}